// Round 8
// baseline (220.057 us; speedup 1.0000x reference)
//
#include <hip/hip_runtime.h>
#include <math.h>

typedef _Float16 f16x2 __attribute__((ext_vector_type(2)));
typedef _Float16 f16x4 __attribute__((ext_vector_type(4)));
typedef _Float16 f16x8 __attribute__((ext_vector_type(8)));
typedef float f32x4 __attribute__((ext_vector_type(4)));

#define DIM 128
#define LDST 136   // padded LDS row stride in f16 elems (272B, 16B-aligned)
#define KVR 256    // interleaved record: k int8 [0,128) | v biased-uint8 [128,256)

#if defined(__has_builtin)
#if __has_builtin(__builtin_amdgcn_sdot4)
#define HAVE_SDOT4 1
#endif
#if __has_builtin(__builtin_amdgcn_perm)
#define HAVE_PERM 1
#endif
#if __has_builtin(__builtin_amdgcn_exp2f)
#define HAVE_EXP2 1
#endif
#endif

__device__ __forceinline__ float fast_exp2(float x) {
#ifdef HAVE_EXP2
    return __builtin_amdgcn_exp2f(x);
#else
    return exp2f(x);
#endif
}

// 4-byte int8 dot product: d += dot(a.4xi8, b.4xi8)
__device__ __forceinline__ int dot4i8(int a, int b, int c) {
#ifdef HAVE_SDOT4
    return __builtin_amdgcn_sdot4(a, b, c, false);
#else
    int s = c;
#pragma unroll
    for (int j = 0; j < 4; ++j)
        s += (int)((signed char)((a >> (8 * j)) & 0xff)) *
             (int)((signed char)((b >> (8 * j)) & 0xff));
    return s;
#endif
}

union U32H2 { unsigned int u; f16x2 h; };

// biased-uint8 pair -> f16 pair (1024+b0, 1024+b1) via one v_perm_b32.
// f16 bit pattern 0x6400|b == 1024+b exactly for b in [0,255].
__device__ __forceinline__ f16x2 byte2f16(unsigned int w, unsigned int sel) {
    U32H2 u;
#ifdef HAVE_PERM
    u.u = __builtin_amdgcn_perm(0x64646464u, w, sel);
#else
    unsigned b0 = (w >> (8 * (sel & 3))) & 0xff;
    unsigned b1 = (w >> (8 * ((sel >> 16) & 3))) & 0xff;
    u.u = 0x64006400u | b0 | (b1 << 16);
#endif
    return u.h;
}

// ---------------------------------------------------------------------------
// Kernel 1: setup — fused weight transpose/f16-convert + CSR row_ptr build.
// ---------------------------------------------------------------------------
__global__ __launch_bounds__(256) void setup_kernel(
    const float* __restrict__ Wq, const float* __restrict__ Wk,
    const float* __restrict__ Wv, _Float16* __restrict__ Wt,
    const int* __restrict__ rows, int* __restrict__ row_ptr, int n, int e)
{
    int b = blockIdx.x;
    if (b < 192) {
        int mat = b >> 6;
        const float* W = (mat == 0) ? Wq : (mat == 1) ? Wk : Wv;
        _Float16* dst = Wt + (size_t)mat * DIM * DIM;
        int idx = (b & 63) * 256 + threadIdx.x;
        int k = idx >> 7;
        int c = idx & 127;
        dst[c * DIM + k] = (_Float16)W[idx];
    } else {
        int r = (b - 192) * 256 + threadIdx.x;
        if (r > n) return;
        if (r == n) { row_ptr[n] = e; return; }
        int lo = 0, hi = e;
        while (lo < hi) {
            int mid = (lo + hi) >> 1;
            if (rows[mid] < r) lo = mid + 1; else hi = mid;
        }
        row_ptr[r] = lo;
    }
}

// ---------------------------------------------------------------------------
// Kernel 2: fused projection GEMM  Y = gelu(X @ W + b), int8 per-row scale.
//   which==0 -> q8i (signed int8) + sclq
//   which==1 -> kv record bytes [0,128)  (signed int8 k) + scl2[].x
//   which==2 -> kv record bytes [128,256) (BIASED uint8 v = q+128) + scl2[].y
// ---------------------------------------------------------------------------
__global__ __launch_bounds__(256, 3) void proj_gemm_kernel(
    const float* __restrict__ query, const float* __restrict__ memory,
    const _Float16* __restrict__ Wt,
    const float* __restrict__ bq, const float* __restrict__ bk,
    const float* __restrict__ bv,
    unsigned char* __restrict__ q8i, float* __restrict__ sclq,
    unsigned char* __restrict__ kv, float2* __restrict__ scl2,
    int n, int m)
{
    __shared__ _Float16 xs[128 * LDST];   // 34816 B

    int which = blockIdx.y;
    const float* X     = (which == 0) ? query : memory;
    const _Float16* Wm = Wt + (size_t)which * DIM * DIM;
    const float* bias  = (which == 0) ? bq : (which == 1) ? bk : bv;
    int R              = (which == 0) ? n : m;

    int tid = threadIdx.x;
    int rowblock = blockIdx.x * 128;
    if (rowblock >= R) return;

    for (int it = 0; it < 16; ++it) {
        int flat = it * 256 + tid;
        int r  = flat >> 5;
        int c4 = (flat & 31) * 4;
        int gr = rowblock + r;
        if (gr >= R) gr = R - 1;
        float4 x = *(const float4*)(X + (size_t)gr * DIM + c4);
        f16x4 w4;
        w4[0] = (_Float16)x.x; w4[1] = (_Float16)x.y;
        w4[2] = (_Float16)x.z; w4[3] = (_Float16)x.w;
        *(f16x4*)(&xs[r * LDST + c4]) = w4;
    }
    __syncthreads();

    int wave = tid >> 6;
    int lane = tid & 63;
    int quad = lane >> 4;
    int l16  = lane & 15;
    int wrow = wave * 32;

    f16x8 afrag[2][4];
    for (int rt = 0; rt < 2; ++rt)
        for (int ks = 0; ks < 4; ++ks)
            afrag[rt][ks] = *(const f16x8*)(&xs[(wrow + rt * 16 + l16) * LDST + quad * 8 + ks * 32]);

    f32x4 acc[8][2];
    for (int ct = 0; ct < 8; ++ct) { acc[ct][0] = {0,0,0,0}; acc[ct][1] = {0,0,0,0}; }
    for (int ct = 0; ct < 8; ++ct) {
        const _Float16* wp = Wm + (size_t)(ct * 16 + l16) * DIM + quad * 8;
        for (int ks = 0; ks < 4; ++ks) {
            f16x8 b = *(const f16x8*)(wp + ks * 32);
            acc[ct][0] = __builtin_amdgcn_mfma_f32_16x16x32_f16(afrag[0][ks], b, acc[ct][0], 0, 0, 0);
            acc[ct][1] = __builtin_amdgcn_mfma_f32_16x16x32_f16(afrag[1][ks], b, acc[ct][1], 0, 0, 0);
        }
    }

    __syncthreads();
    for (int ct = 0; ct < 8; ++ct) {
        float bval = bias[ct * 16 + l16];
        for (int rt = 0; rt < 2; ++rt) {
            for (int reg = 0; reg < 4; ++reg) {
                float x = acc[ct][rt][reg] + bval;
                float t  = 0.7978845608028654f * (x + 0.044715f * x * x * x);
                float th = 1.0f - 2.0f / (__expf(2.0f * t) + 1.0f);
                float g  = 0.5f * x * (1.0f + th);
                xs[(wrow + rt * 16 + quad * 4 + reg) * LDST + ct * 16 + l16] = (_Float16)g;
            }
        }
    }
    __syncthreads();

    int qbias = (which == 2) ? 128 : 0;
    // int8 per-row quant. In each it, the 16-lane group (flat&15) covers the
    // FULL 128-dim row r -> row-max via 4 shfl_xor steps (16-aligned groups).
    for (int it = 0; it < 8; ++it) {
        int flat = it * 256 + tid;
        int r  = flat >> 4;
        int c8 = (flat & 15) * 8;
        int gr = rowblock + r;
        f16x8 h = *(const f16x8*)(&xs[r * LDST + c8]);
        float f[8];
        float mx = 0.0f;
#pragma unroll
        for (int j = 0; j < 8; ++j) {
            f[j] = (float)h[j];
            mx = fmaxf(mx, fabsf(f[j]));
        }
        mx = fmaxf(mx, __shfl_xor(mx, 1));
        mx = fmaxf(mx, __shfl_xor(mx, 2));
        mx = fmaxf(mx, __shfl_xor(mx, 4));
        mx = fmaxf(mx, __shfl_xor(mx, 8));
        float qs = (mx > 0.0f) ? 127.0f / mx : 0.0f;
        if (gr < R) {
            unsigned int w0 = 0, w1 = 0;
#pragma unroll
            for (int j = 0; j < 4; ++j) {
                int q = (int)rintf(fminf(fmaxf(f[j] * qs, -127.0f), 127.0f)) + qbias;
                w0 |= ((unsigned int)(q & 0xff)) << (8 * j);
            }
#pragma unroll
            for (int j = 0; j < 4; ++j) {
                int q = (int)rintf(fminf(fmaxf(f[4 + j] * qs, -127.0f), 127.0f)) + qbias;
                w1 |= ((unsigned int)(q & 0xff)) << (8 * j);
            }
            if (which == 0)
                *(uint2*)(q8i + (size_t)gr * DIM + c8) = make_uint2(w0, w1);
            else if (which == 1)
                *(uint2*)(kv + (size_t)gr * KVR + c8) = make_uint2(w0, w1);
            else
                *(uint2*)(kv + (size_t)gr * KVR + 128 + c8) = make_uint2(w0, w1);
            if ((flat & 15) == 0) {
                float ds = mx * (1.0f / 127.0f);
                if (which == 0)      sclq[gr]   = ds;
                else if (which == 1) scl2[gr].x = ds;
                else                 scl2[gr].y = ds;
            }
        }
    }
}

// ---------------------------------------------------------------------------
// Kernel 3: per-row edge attention. 8 lanes/edge x 16B/lane, int8 sdot4
// score path, magic-bias f16 PV (R7 body). R8 change: DEPTH-1 ROTATED
// PIPELINE — at the top of iteration t, issue iteration t+1's full chain
// (cols/adj/scl2 + both kv gathers) into named _next registers; rotate at
// the bottom. Overlaps the gather latency with the current iteration's
// dot/exp/PV (~140cyc) x 8 resident waves. R1 (depth-1, best-ever 60 G/s
// service rate) proved this structure; R2's failure was 4-deep + chunked
// shfl clamps, not rotation itself. VGPR ~50 (< 64 cliff).
// ---------------------------------------------------------------------------
__global__ __launch_bounds__(256) void edge_attn_kernel(
    const unsigned char* __restrict__ q8i, const float* __restrict__ sclq,
    const unsigned char* __restrict__ kv, const float2* __restrict__ scl2,
    const float* __restrict__ adj_vals, const int* __restrict__ cols,
    const int* __restrict__ row_ptr, float* __restrict__ out, int n)
{
    int row = blockIdx.x * 4 + (threadIdx.x >> 6);
    if (row >= n) return;
    int lane = threadIdx.x & 63;
    int g    = lane >> 3;    // edge slot
    int d8   = lane & 7;     // dim slot: dims [d8*16, d8*16+16)

    int start = row_ptr[row];
    int end   = row_ptr[row + 1];

    if (start >= end) {      // empty row -> zeros (prologue would OOB)
        if (g == 0) {
            float4 z = make_float4(0.0f, 0.0f, 0.0f, 0.0f);
            float4* dst = (float4*)(out + (size_t)row * DIM + d8 * 16);
            dst[0] = z; dst[1] = z; dst[2] = z; dst[3] = z;
        }
        return;
    }
    int last = end - 1;

    int4  qw = *(const int4*)(q8i + (size_t)row * DIM + d8 * 16);
    // row-constant: sq * 1/sqrt(128) * log2(e)
    float csr = sclq[row] * (0.08838834764831845f * 1.442695040888963f);

    float s_sum = 0.0f;
    float spsv  = 0.0f;
    float acc[16];
#pragma unroll
    for (int j = 0; j < 16; ++j) acc[j] = 0.0f;

    // prologue: first iteration's chain
    int   i0 = start + g; i0 = (i0 < last) ? i0 : last;
    int   c  = cols[i0];
    float a  = adj_vals[i0];
    float2 sk = scl2[c];
    const unsigned char* base = kv + (size_t)c * KVR + d8 * 16;
    int4 kw = *(const int4*)base;
    int4 vw = *(const int4*)(base + 128);

    for (int gg = start; gg < end; gg += 8) {
        bool vld  = (gg + g) < end;
        bool hasN = (gg + 8) < end;     // wave-uniform

        // issue next iteration's chain before touching current's data
        int cN; float aN; float2 skN; int4 kwN, vwN;
        if (hasN) {
            int iN = gg + 8 + g; iN = (iN < last) ? iN : last;
            cN  = cols[iN];
            aN  = adj_vals[iN];
            skN = scl2[cN];
            const unsigned char* bN = kv + (size_t)cN * KVR + d8 * 16;
            kwN = *(const int4*)bN;
            vwN = *(const int4*)(bN + 128);
        }

        int di = dot4i8(qw.x, kw.x, 0);
        di = dot4i8(qw.y, kw.y, di);
        di = dot4i8(qw.z, kw.z, di);
        di = dot4i8(qw.w, kw.w, di);
        di += __shfl_xor(di, 1);
        di += __shfl_xor(di, 2);
        di += __shfl_xor(di, 4);

        float p = vld ? fast_exp2((float)di * (csr * sk.x * a)) : 0.0f;
        s_sum += p;

        float psv = p * sk.y;   // fold v dequant scale into weight
        spsv += psv;
#pragma unroll
        for (int d = 0; d < 4; ++d) {
            unsigned int w = (d == 0) ? (unsigned int)vw.x : (d == 1) ? (unsigned int)vw.y
                           : (d == 2) ? (unsigned int)vw.z : (unsigned int)vw.w;
            f16x2 lo = byte2f16(w, 0x04010400u);   // (1024+b0, 1024+b1)
            f16x2 hi = byte2f16(w, 0x04030402u);   // (1024+b2, 1024+b3)
            acc[4 * d]     += psv * (float)lo[0];  // v_fma_mix_f32
            acc[4 * d + 1] += psv * (float)lo[1];
            acc[4 * d + 2] += psv * (float)hi[0];
            acc[4 * d + 3] += psv * (float)hi[1];
        }

        if (hasN) { c = cN; a = aN; sk = skN; kw = kwN; vw = vwN; }
    }

    // remove the 1024+128 unpack bias: each raw = 1152 + q
#pragma unroll
    for (int j = 0; j < 16; ++j) acc[j] -= 1152.0f * spsv;

    // merge the 8 edge slots (lane bits 3..5)
    s_sum += __shfl_xor(s_sum, 8);
    s_sum += __shfl_xor(s_sum, 16);
    s_sum += __shfl_xor(s_sum, 32);
#pragma unroll
    for (int j = 0; j < 16; ++j) {
        acc[j] += __shfl_xor(acc[j], 8);
        acc[j] += __shfl_xor(acc[j], 16);
        acc[j] += __shfl_xor(acc[j], 32);
    }
    float inv = (s_sum > 0.0f) ? 1.0f / s_sum : 0.0f;

    if (g == 0) {
        float4* dst = (float4*)(out + (size_t)row * DIM + d8 * 16);
#pragma unroll
        for (int j = 0; j < 4; ++j)
            dst[j] = make_float4(acc[4 * j] * inv, acc[4 * j + 1] * inv,
                                 acc[4 * j + 2] * inv, acc[4 * j + 3] * inv);
    }
}

// ---------------------------------------------------------------------------
extern "C" void kernel_launch(void* const* d_in, const int* in_sizes, int n_in,
                              void* d_out, int out_size, void* d_ws, size_t ws_size,
                              hipStream_t stream)
{
    const float* query    = (const float*)d_in[0];
    const float* memory   = (const float*)d_in[1];
    const float* adj_vals = (const float*)d_in[2];
    const float* Wq       = (const float*)d_in[3];
    const float* bq       = (const float*)d_in[4];
    const float* Wk       = (const float*)d_in[5];
    const float* bk       = (const float*)d_in[6];
    const float* Wv       = (const float*)d_in[7];
    const float* bv       = (const float*)d_in[8];
    const int*   rows     = (const int*)d_in[9];
    const int*   cols     = (const int*)d_in[10];
    float* out = (float*)d_out;

    int n = in_sizes[0] / DIM;   // 50000
    int m = in_sizes[1] / DIM;   // 50000
    int e = in_sizes[9];         // 1600000

    // workspace layout (16B-aligned)
    char* ws = (char*)d_ws;
    size_t off = 0;
    _Float16* Wt = (_Float16*)(ws + off);            off += (size_t)3 * DIM * DIM * 2; // 98KB
    unsigned char* q8i = (unsigned char*)(ws + off); off += (size_t)n * DIM;           // 6.4MB
    unsigned char* kv  = (unsigned char*)(ws + off); off += (size_t)m * KVR;           // 12.8MB
    float* sclq  = (float*)(ws + off);               off += (size_t)n * 4;             // 200KB
    float2* scl2 = (float2*)(ws + off);              off += (size_t)m * 8;             // 400KB
    int* row_ptr = (int*)(ws + off);                 off += (size_t)(n + 1) * 4;

    int rp_blocks = (n + 1 + 255) / 256;
    setup_kernel<<<dim3(192 + rp_blocks), 256, 0, stream>>>(
        Wq, Wk, Wv, Wt, rows, row_ptr, n, e);

    proj_gemm_kernel<<<dim3((n + 127) / 128, 3), 256, 0, stream>>>(
        query, memory, Wt, bq, bk, bv, q8i, sclq, kv, scl2, n, m);

    edge_attn_kernel<<<dim3((n + 3) / 4), 256, 0, stream>>>(
        q8i, sclq, kv, scl2, adj_vals, cols, row_ptr, out, n);
}

// Round 10
// 220.001 us; speedup vs baseline: 1.0003x; 1.0003x over previous
//
#include <hip/hip_runtime.h>
#include <math.h>

typedef _Float16 f16x2 __attribute__((ext_vector_type(2)));
typedef _Float16 f16x4 __attribute__((ext_vector_type(4)));
typedef _Float16 f16x8 __attribute__((ext_vector_type(8)));
typedef float f32x4 __attribute__((ext_vector_type(4)));

#define DIM 128
#define LDST 136   // padded LDS row stride in f16 elems (272B, 16B-aligned)
#define KVR 256    // interleaved record: k int8 [0,128) | v biased-uint8 [128,256)

#if defined(__has_builtin)
#if __has_builtin(__builtin_amdgcn_sdot4)
#define HAVE_SDOT4 1
#endif
#if __has_builtin(__builtin_amdgcn_perm)
#define HAVE_PERM 1
#endif
#if __has_builtin(__builtin_amdgcn_exp2f)
#define HAVE_EXP2 1
#endif
#endif

__device__ __forceinline__ float fast_exp2(float x) {
#ifdef HAVE_EXP2
    return __builtin_amdgcn_exp2f(x);
#else
    return exp2f(x);
#endif
}

// 4-byte int8 dot product: d += dot(a.4xi8, b.4xi8)
__device__ __forceinline__ int dot4i8(int a, int b, int c) {
#ifdef HAVE_SDOT4
    return __builtin_amdgcn_sdot4(a, b, c, false);
#else
    int s = c;
#pragma unroll
    for (int j = 0; j < 4; ++j)
        s += (int)((signed char)((a >> (8 * j)) & 0xff)) *
             (int)((signed char)((b >> (8 * j)) & 0xff));
    return s;
#endif
}

union U32H2 { unsigned int u; f16x2 h; };

// biased-uint8 pair -> f16 pair (1024+b0, 1024+b1) via one v_perm_b32.
// f16 bit pattern 0x6400|b == 1024+b exactly for b in [0,255].
__device__ __forceinline__ f16x2 byte2f16(unsigned int w, unsigned int sel) {
    U32H2 u;
#ifdef HAVE_PERM
    u.u = __builtin_amdgcn_perm(0x64646464u, w, sel);
#else
    unsigned b0 = (w >> (8 * (sel & 3))) & 0xff;
    unsigned b1 = (w >> (8 * ((sel >> 16) & 3))) & 0xff;
    u.u = 0x64006400u | b0 | (b1 << 16);
#endif
    return u.h;
}

// ---------------------------------------------------------------------------
// Kernel 1: setup — fused weight transpose/f16-convert + CSR row_ptr build.
// ---------------------------------------------------------------------------
__global__ __launch_bounds__(256) void setup_kernel(
    const float* __restrict__ Wq, const float* __restrict__ Wk,
    const float* __restrict__ Wv, _Float16* __restrict__ Wt,
    const int* __restrict__ rows, int* __restrict__ row_ptr, int n, int e)
{
    int b = blockIdx.x;
    if (b < 192) {
        int mat = b >> 6;
        const float* W = (mat == 0) ? Wq : (mat == 1) ? Wk : Wv;
        _Float16* dst = Wt + (size_t)mat * DIM * DIM;
        int idx = (b & 63) * 256 + threadIdx.x;
        int k = idx >> 7;
        int c = idx & 127;
        dst[c * DIM + k] = (_Float16)W[idx];
    } else {
        int r = (b - 192) * 256 + threadIdx.x;
        if (r > n) return;
        if (r == n) { row_ptr[n] = e; return; }
        int lo = 0, hi = e;
        while (lo < hi) {
            int mid = (lo + hi) >> 1;
            if (rows[mid] < r) lo = mid + 1; else hi = mid;
        }
        row_ptr[r] = lo;
    }
}

// ---------------------------------------------------------------------------
// Kernel 2: fused projection GEMM  Y = gelu(X @ W + b), int8 per-row scale.
//   which==0 -> q8i (signed int8) + sclq
//   which==1 -> kv record bytes [0,128)  (signed int8 k) + scl2[].x
//   which==2 -> kv record bytes [128,256) (BIASED uint8 v = q+128) + scl2[].y
// The bias enables the edge kernel's 0x6400|b f16 unpack trick; the
// constant folds out via spsv there.
// ---------------------------------------------------------------------------
__global__ __launch_bounds__(256, 3) void proj_gemm_kernel(
    const float* __restrict__ query, const float* __restrict__ memory,
    const _Float16* __restrict__ Wt,
    const float* __restrict__ bq, const float* __restrict__ bk,
    const float* __restrict__ bv,
    unsigned char* __restrict__ q8i, float* __restrict__ sclq,
    unsigned char* __restrict__ kv, float2* __restrict__ scl2,
    int n, int m)
{
    __shared__ _Float16 xs[128 * LDST];   // 34816 B

    int which = blockIdx.y;
    const float* X     = (which == 0) ? query : memory;
    const _Float16* Wm = Wt + (size_t)which * DIM * DIM;
    const float* bias  = (which == 0) ? bq : (which == 1) ? bk : bv;
    int R              = (which == 0) ? n : m;

    int tid = threadIdx.x;
    int rowblock = blockIdx.x * 128;
    if (rowblock >= R) return;

    for (int it = 0; it < 16; ++it) {
        int flat = it * 256 + tid;
        int r  = flat >> 5;
        int c4 = (flat & 31) * 4;
        int gr = rowblock + r;
        if (gr >= R) gr = R - 1;
        float4 x = *(const float4*)(X + (size_t)gr * DIM + c4);
        f16x4 w4;
        w4[0] = (_Float16)x.x; w4[1] = (_Float16)x.y;
        w4[2] = (_Float16)x.z; w4[3] = (_Float16)x.w;
        *(f16x4*)(&xs[r * LDST + c4]) = w4;
    }
    __syncthreads();

    int wave = tid >> 6;
    int lane = tid & 63;
    int quad = lane >> 4;
    int l16  = lane & 15;
    int wrow = wave * 32;

    f16x8 afrag[2][4];
    for (int rt = 0; rt < 2; ++rt)
        for (int ks = 0; ks < 4; ++ks)
            afrag[rt][ks] = *(const f16x8*)(&xs[(wrow + rt * 16 + l16) * LDST + quad * 8 + ks * 32]);

    f32x4 acc[8][2];
    for (int ct = 0; ct < 8; ++ct) { acc[ct][0] = {0,0,0,0}; acc[ct][1] = {0,0,0,0}; }
    for (int ct = 0; ct < 8; ++ct) {
        const _Float16* wp = Wm + (size_t)(ct * 16 + l16) * DIM + quad * 8;
        for (int ks = 0; ks < 4; ++ks) {
            f16x8 b = *(const f16x8*)(wp + ks * 32);
            acc[ct][0] = __builtin_amdgcn_mfma_f32_16x16x32_f16(afrag[0][ks], b, acc[ct][0], 0, 0, 0);
            acc[ct][1] = __builtin_amdgcn_mfma_f32_16x16x32_f16(afrag[1][ks], b, acc[ct][1], 0, 0, 0);
        }
    }

    __syncthreads();
    for (int ct = 0; ct < 8; ++ct) {
        float bval = bias[ct * 16 + l16];
        for (int rt = 0; rt < 2; ++rt) {
            for (int reg = 0; reg < 4; ++reg) {
                float x = acc[ct][rt][reg] + bval;
                float t  = 0.7978845608028654f * (x + 0.044715f * x * x * x);
                float th = 1.0f - 2.0f / (__expf(2.0f * t) + 1.0f);
                float g  = 0.5f * x * (1.0f + th);
                xs[(wrow + rt * 16 + quad * 4 + reg) * LDST + ct * 16 + l16] = (_Float16)g;
            }
        }
    }
    __syncthreads();

    int qbias = (which == 2) ? 128 : 0;
    // int8 per-row quant. In each it, the 16-lane group (flat&15) covers the
    // FULL 128-dim row r -> row-max via 4 shfl_xor steps (16-aligned groups).
    for (int it = 0; it < 8; ++it) {
        int flat = it * 256 + tid;
        int r  = flat >> 4;
        int c8 = (flat & 15) * 8;
        int gr = rowblock + r;
        f16x8 h = *(const f16x8*)(&xs[r * LDST + c8]);
        float f[8];
        float mx = 0.0f;
#pragma unroll
        for (int j = 0; j < 8; ++j) {
            f[j] = (float)h[j];
            mx = fmaxf(mx, fabsf(f[j]));
        }
        mx = fmaxf(mx, __shfl_xor(mx, 1));
        mx = fmaxf(mx, __shfl_xor(mx, 2));
        mx = fmaxf(mx, __shfl_xor(mx, 4));
        mx = fmaxf(mx, __shfl_xor(mx, 8));
        float qs = (mx > 0.0f) ? 127.0f / mx : 0.0f;
        if (gr < R) {
            unsigned int w0 = 0, w1 = 0;
#pragma unroll
            for (int j = 0; j < 4; ++j) {
                int q = (int)rintf(fminf(fmaxf(f[j] * qs, -127.0f), 127.0f)) + qbias;
                w0 |= ((unsigned int)(q & 0xff)) << (8 * j);
            }
#pragma unroll
            for (int j = 0; j < 4; ++j) {
                int q = (int)rintf(fminf(fmaxf(f[4 + j] * qs, -127.0f), 127.0f)) + qbias;
                w1 |= ((unsigned int)(q & 0xff)) << (8 * j);
            }
            if (which == 0)
                *(uint2*)(q8i + (size_t)gr * DIM + c8) = make_uint2(w0, w1);
            else if (which == 1)
                *(uint2*)(kv + (size_t)gr * KVR + c8) = make_uint2(w0, w1);
            else
                *(uint2*)(kv + (size_t)gr * KVR + 128 + c8) = make_uint2(w0, w1);
            if ((flat & 15) == 0) {
                float ds = mx * (1.0f / 127.0f);
                if (which == 0)      sclq[gr]   = ds;
                else if (which == 1) scl2[gr].x = ds;
                else                 scl2[gr].y = ds;
            }
        }
    }
}

// ---------------------------------------------------------------------------
// Kernel 3: per-row edge attention — R7 body (session best: 63.7us).
// 8 lanes/edge x 16B/lane; interleaved kv record (one gather base/edge,
// v at offset 128); int8 sdot4 score path; PV via v_perm magic-bias
// (0x6400|b == 1024+b in f16) + v_fma_mix_f32 with the 1152 bias folded
// out through spsv; exp2 with log2e folded into the row constant.
// NOTE: no software pipelining — depth-1 rotation (R8), 4-slot (R2) and
// persistent grid (R3) all measured slower; 8-wave TLP at occupancy ~67%
// covers what latency can be covered at this service rate.
// ---------------------------------------------------------------------------
__global__ __launch_bounds__(256) void edge_attn_kernel(
    const unsigned char* __restrict__ q8i, const float* __restrict__ sclq,
    const unsigned char* __restrict__ kv, const float2* __restrict__ scl2,
    const float* __restrict__ adj_vals, const int* __restrict__ cols,
    const int* __restrict__ row_ptr, float* __restrict__ out, int n)
{
    int row = blockIdx.x * 4 + (threadIdx.x >> 6);
    if (row >= n) return;
    int lane = threadIdx.x & 63;
    int g    = lane >> 3;    // edge slot
    int d8   = lane & 7;     // dim slot: dims [d8*16, d8*16+16)

    int start = row_ptr[row];
    int end   = row_ptr[row + 1];

    int4  qw = *(const int4*)(q8i + (size_t)row * DIM + d8 * 16);
    // row-constant: sq * 1/sqrt(128) * log2(e)
    float csr = sclq[row] * (0.08838834764831845f * 1.442695040888963f);

    float s_sum = 0.0f;
    float spsv  = 0.0f;
    float acc[16];
#pragma unroll
    for (int j = 0; j < 16; ++j) acc[j] = 0.0f;

    for (int gg = start; gg < end; gg += 8) {
        int e     = gg + g;
        bool vld  = e < end;
        int  i    = vld ? e : end - 1;
        int  c    = cols[i];
        float a   = adj_vals[i];
        float2 sk = scl2[c];

        const unsigned char* base = kv + (size_t)c * KVR + d8 * 16;
        int4 kw = *(const int4*)base;
        int4 vw = *(const int4*)(base + 128);

        int di = dot4i8(qw.x, kw.x, 0);
        di = dot4i8(qw.y, kw.y, di);
        di = dot4i8(qw.z, kw.z, di);
        di = dot4i8(qw.w, kw.w, di);
        di += __shfl_xor(di, 1);
        di += __shfl_xor(di, 2);
        di += __shfl_xor(di, 4);

        float p = vld ? fast_exp2((float)di * (csr * sk.x * a)) : 0.0f;
        s_sum += p;

        float psv = p * sk.y;   // fold v dequant scale into weight
        spsv += psv;
#pragma unroll
        for (int d = 0; d < 4; ++d) {
            unsigned int w = (d == 0) ? (unsigned int)vw.x : (d == 1) ? (unsigned int)vw.y
                           : (d == 2) ? (unsigned int)vw.z : (unsigned int)vw.w;
            f16x2 lo = byte2f16(w, 0x04010400u);   // (1024+b0, 1024+b1)
            f16x2 hi = byte2f16(w, 0x04030402u);   // (1024+b2, 1024+b3)
            acc[4 * d]     += psv * (float)lo[0];  // v_fma_mix_f32
            acc[4 * d + 1] += psv * (float)lo[1];
            acc[4 * d + 2] += psv * (float)hi[0];
            acc[4 * d + 3] += psv * (float)hi[1];
        }
    }

    // remove the 1024+128 unpack bias: each raw = 1152 + q
#pragma unroll
    for (int j = 0; j < 16; ++j) acc[j] -= 1152.0f * spsv;

    // merge the 8 edge slots (lane bits 3..5)
    s_sum += __shfl_xor(s_sum, 8);
    s_sum += __shfl_xor(s_sum, 16);
    s_sum += __shfl_xor(s_sum, 32);
#pragma unroll
    for (int j = 0; j < 16; ++j) {
        acc[j] += __shfl_xor(acc[j], 8);
        acc[j] += __shfl_xor(acc[j], 16);
        acc[j] += __shfl_xor(acc[j], 32);
    }
    float inv = (s_sum > 0.0f) ? 1.0f / s_sum : 0.0f;   // empty row -> zeros

    if (g == 0) {
        float4* dst = (float4*)(out + (size_t)row * DIM + d8 * 16);
#pragma unroll
        for (int j = 0; j < 4; ++j)
            dst[j] = make_float4(acc[4 * j] * inv, acc[4 * j + 1] * inv,
                                 acc[4 * j + 2] * inv, acc[4 * j + 3] * inv);
    }
}

// ---------------------------------------------------------------------------
extern "C" void kernel_launch(void* const* d_in, const int* in_sizes, int n_in,
                              void* d_out, int out_size, void* d_ws, size_t ws_size,
                              hipStream_t stream)
{
    const float* query    = (const float*)d_in[0];
    const float* memory   = (const float*)d_in[1];
    const float* adj_vals = (const float*)d_in[2];
    const float* Wq       = (const float*)d_in[3];
    const float* bq       = (const float*)d_in[4];
    const float* Wk       = (const float*)d_in[5];
    const float* bk       = (const float*)d_in[6];
    const float* Wv       = (const float*)d_in[7];
    const float* bv       = (const float*)d_in[8];
    const int*   rows     = (const int*)d_in[9];
    const int*   cols     = (const int*)d_in[10];
    float* out = (float*)d_out;

    int n = in_sizes[0] / DIM;   // 50000
    int m = in_sizes[1] / DIM;   // 50000
    int e = in_sizes[9];         // 1600000

    // workspace layout (16B-aligned)
    char* ws = (char*)d_ws;
    size_t off = 0;
    _Float16* Wt = (_Float16*)(ws + off);            off += (size_t)3 * DIM * DIM * 2; // 98KB
    unsigned char* q8i = (unsigned char*)(ws + off); off += (size_t)n * DIM;           // 6.4MB
    unsigned char* kv  = (unsigned char*)(ws + off); off += (size_t)m * KVR;           // 12.8MB
    float* sclq  = (float*)(ws + off);               off += (size_t)n * 4;             // 200KB
    float2* scl2 = (float2*)(ws + off);              off += (size_t)m * 8;             // 400KB
    int* row_ptr = (int*)(ws + off);                 off += (size_t)(n + 1) * 4;

    int rp_blocks = (n + 1 + 255) / 256;
    setup_kernel<<<dim3(192 + rp_blocks), 256, 0, stream>>>(
        Wq, Wk, Wv, Wt, rows, row_ptr, n, e);

    proj_gemm_kernel<<<dim3((n + 127) / 128, 3), 256, 0, stream>>>(
        query, memory, Wt, bq, bk, bv, q8i, sclq, kv, scl2, n, m);

    edge_attn_kernel<<<dim3((n + 3) / 4), 256, 0, stream>>>(
        q8i, sclq, kv, scl2, adj_vals, cols, row_ptr, out, n);
}